// Round 1
// baseline (1091.296 us; speedup 1.0000x reference)
//
#include <hip/hip_runtime.h>

#define NN 200000
#define NE 6400000
#define F1 16

// ws layout (floats):
//   deg/dinv : [0,            NN)           — deg then overwritten by dinv
//   hs       : [NN,           NN+16NN)      — h1_pre * dinv[src]
//   acc1     : [NN+16NN,      NN+32NN)
//   hs2      : [NN+32NN,      NN+35NN)
//   acc2     : [NN+35NN,      NN+38NN)
#define OFF_DEG  0
#define OFF_HS   (NN)
#define OFF_ACC1 (NN + 16*NN)
#define OFF_HS2  (NN + 32*NN)
#define OFF_ACC2 (NN + 35*NN)

__global__ void k_init(float* __restrict__ ws) {
    int i = blockIdx.x * blockDim.x + threadIdx.x;
    int stride = gridDim.x * blockDim.x;
    for (int v = i; v < NN; v += stride) ws[OFF_DEG + v] = 1.0f;       // self loop
    for (int j = i; j < 16 * NN; j += stride) ws[OFF_ACC1 + j] = 0.0f;
    for (int j = i; j < 3 * NN; j += stride) ws[OFF_ACC2 + j] = 0.0f;
}

__global__ void k_deg(const int* __restrict__ dst, float* __restrict__ deg) {
    int e = blockIdx.x * blockDim.x + threadIdx.x;
    if (e < NE) atomicAdd(&deg[dst[e]], 1.0f);
}

// per node: dinv = rsqrt(deg); h = x@W1; hs = h*dinv  (deg overwritten by dinv)
__global__ void k_node1(const float* __restrict__ x, const float* __restrict__ W1,
                        float* __restrict__ ws) {
    __shared__ float sW[48];
    if (threadIdx.x < 48) sW[threadIdx.x] = W1[threadIdx.x];
    __syncthreads();
    int v = blockIdx.x * blockDim.x + threadIdx.x;
    if (v >= NN) return;
    float di = rsqrtf(ws[OFF_DEG + v]);
    ws[OFF_DEG + v] = di;   // deg -> dinv in place
    float x0 = x[3 * v], x1 = x[3 * v + 1], x2 = x[3 * v + 2];
    float out[16];
#pragma unroll
    for (int j = 0; j < 16; ++j)
        out[j] = (x0 * sW[j] + x1 * sW[16 + j] + x2 * sW[32 + j]) * di;
    float4* hv = (float4*)(ws + OFF_HS + (size_t)v * 16);
#pragma unroll
    for (int r = 0; r < 4; ++r)
        hv[r] = make_float4(out[4 * r], out[4 * r + 1], out[4 * r + 2], out[4 * r + 3]);
}

// 16 lanes per edge: lane k does acc1[dst*16+k] += hs[src*16+k]
__global__ void k_edge1(const int* __restrict__ src, const int* __restrict__ dst,
                        const float* __restrict__ ws_ro, float* __restrict__ ws) {
    long long t = (long long)blockIdx.x * blockDim.x + threadIdx.x;
    long long e = t >> 4;
    int k = (int)(t & 15);
    if (e >= NE) return;
    int s = src[e], d = dst[e];
    float val = ws_ro[OFF_HS + (size_t)s * 16 + k];
    atomicAdd(ws + OFF_ACC1 + (size_t)d * 16 + k, val);
}

// per node: h1 = relu(dinv*(acc1+hs)+b1); h2 = h1@W2; hs2 = h2*dinv
__global__ void k_node2(const float* __restrict__ b1, const float* __restrict__ W2,
                        float* __restrict__ ws) {
    __shared__ float sW[48];
    __shared__ float sb[16];
    if (threadIdx.x < 48) sW[threadIdx.x] = W2[threadIdx.x];
    if (threadIdx.x < 16) sb[threadIdx.x] = b1[threadIdx.x];
    __syncthreads();
    int v = blockIdx.x * blockDim.x + threadIdx.x;
    if (v >= NN) return;
    float di = ws[OFF_DEG + v];
    const float4* av = (const float4*)(ws + OFF_ACC1 + (size_t)v * 16);
    const float4* hv = (const float4*)(ws + OFF_HS + (size_t)v * 16);
    float h1[16];
#pragma unroll
    for (int r = 0; r < 4; ++r) {
        float4 a = av[r], h = hv[r];
        float t0 = di * (a.x + h.x) + sb[4 * r + 0];
        float t1 = di * (a.y + h.y) + sb[4 * r + 1];
        float t2 = di * (a.z + h.z) + sb[4 * r + 2];
        float t3 = di * (a.w + h.w) + sb[4 * r + 3];
        h1[4 * r + 0] = t0 > 0.f ? t0 : 0.f;
        h1[4 * r + 1] = t1 > 0.f ? t1 : 0.f;
        h1[4 * r + 2] = t2 > 0.f ? t2 : 0.f;
        h1[4 * r + 3] = t3 > 0.f ? t3 : 0.f;
    }
    float o0 = 0.f, o1 = 0.f, o2 = 0.f;
#pragma unroll
    for (int j = 0; j < 16; ++j) {
        o0 += h1[j] * sW[3 * j + 0];
        o1 += h1[j] * sW[3 * j + 1];
        o2 += h1[j] * sW[3 * j + 2];
    }
    ws[OFF_HS2 + (size_t)v * 3 + 0] = o0 * di;
    ws[OFF_HS2 + (size_t)v * 3 + 1] = o1 * di;
    ws[OFF_HS2 + (size_t)v * 3 + 2] = o2 * di;
}

// 4 lanes per edge (3 active): acc2[dst*3+k] += hs2[src*3+k]
__global__ void k_edge2(const int* __restrict__ src, const int* __restrict__ dst,
                        const float* __restrict__ ws_ro, float* __restrict__ ws) {
    long long t = (long long)blockIdx.x * blockDim.x + threadIdx.x;
    long long e = t >> 2;
    int k = (int)(t & 3);
    if (e >= NE || k >= 3) return;
    int s = src[e], d = dst[e];
    float val = ws_ro[OFF_HS2 + (size_t)s * 3 + k];
    atomicAdd(ws + OFF_ACC2 + (size_t)d * 3 + k, val);
}

__global__ void k_out(const float* __restrict__ b2, const float* __restrict__ ws,
                      float* __restrict__ out) {
    int v = blockIdx.x * blockDim.x + threadIdx.x;
    if (v >= NN) return;
    float di = ws[OFF_DEG + v];
    float bb0 = b2[0], bb1 = b2[1], bb2 = b2[2];
    out[3 * v + 0] = di * (ws[OFF_ACC2 + (size_t)v * 3 + 0] + ws[OFF_HS2 + (size_t)v * 3 + 0]) + bb0;
    out[3 * v + 1] = di * (ws[OFF_ACC2 + (size_t)v * 3 + 1] + ws[OFF_HS2 + (size_t)v * 3 + 1]) + bb1;
    out[3 * v + 2] = di * (ws[OFF_ACC2 + (size_t)v * 3 + 2] + ws[OFF_HS2 + (size_t)v * 3 + 2]) + bb2;
}

extern "C" void kernel_launch(void* const* d_in, const int* in_sizes, int n_in,
                              void* d_out, int out_size, void* d_ws, size_t ws_size,
                              hipStream_t stream) {
    const float* x  = (const float*)d_in[0];
    const int* ei   = (const int*)d_in[1];
    const float* W1 = (const float*)d_in[2];
    const float* b1 = (const float*)d_in[3];
    const float* W2 = (const float*)d_in[4];
    const float* b2 = (const float*)d_in[5];
    const int* src = ei;
    const int* dst = ei + NE;
    float* ws = (float*)d_ws;
    float* out = (float*)d_out;

    const int B = 256;
    int gN   = (NN + B - 1) / B;
    int gE   = (NE + B - 1) / B;
    int gE16 = (int)(((long long)NE * 16 + B - 1) / B);
    int gE4  = (int)(((long long)NE * 4 + B - 1) / B);

    k_init<<<8192, B, 0, stream>>>(ws);
    k_deg<<<gE, B, 0, stream>>>(dst, ws + OFF_DEG);
    k_node1<<<gN, B, 0, stream>>>(x, W1, ws);
    k_edge1<<<gE16, B, 0, stream>>>(src, dst, ws, ws);
    k_node2<<<gN, B, 0, stream>>>(b1, W2, ws);
    k_edge2<<<gE4, B, 0, stream>>>(src, dst, ws, ws);
    k_out<<<gN, B, 0, stream>>>(b2, ws, out);
}